// Round 3
// baseline (9.951 us; speedup 1.0000x reference)
//
#include <hip/hip_runtime.h>

#define NQ 8
#define ROWS (16 * 4096)          // BATCH * SEQ
#define EMBED 768
#define NTHREADS (ROWS * 2)       // one thread per half-row (4 outputs)

__global__ __launch_bounds__(256) void qfe_kernel(const float* __restrict__ x,
                                                  const float* __restrict__ theta,
                                                  float* __restrict__ out) {
    int t = blockIdx.x * blockDim.x + threadIdx.x;
    if (t >= NTHREADS) return;
    int row  = t >> 1;
    int half = t & 1;            // which float4 of the row's first 8 floats

    const float4 a = *reinterpret_cast<const float4*>(x + (size_t)row * EMBED + half * 4);

    // theta: 32 B, L1-resident broadcast; 4 scalar loads + 4 cosf per thread
    const float* th = theta + half * 4;
    float4 o;
    o.x = cosf(a.x) * cosf(th[0]);
    o.y = cosf(a.y) * cosf(th[1]);
    o.z = cosf(a.z) * cosf(th[2]);
    o.w = cosf(a.w) * cosf(th[3]);

    *reinterpret_cast<float4*>(out + (size_t)t * 4) = o;
}

extern "C" void kernel_launch(void* const* d_in, const int* in_sizes, int n_in,
                              void* d_out, int out_size, void* d_ws, size_t ws_size,
                              hipStream_t stream) {
    const float* x     = (const float*)d_in[0];
    const float* theta = (const float*)d_in[1];
    float* out         = (float*)d_out;

    dim3 block(256);
    dim3 grid((NTHREADS + 255) / 256);   // 512 blocks
    qfe_kernel<<<grid, block, 0, stream>>>(x, theta, out);
}